// Round 1
// baseline (10162.489 us; speedup 1.0000x reference)
//
#include <hip/hip_runtime.h>

typedef __bf16 bf16;
typedef __bf16 bf16x8 __attribute__((ext_vector_type(8)));
typedef __bf16 bf16x4 __attribute__((ext_vector_type(4)));
typedef float  f32x4  __attribute__((ext_vector_type(4)));

#define T_LEN 70
#define BATCH 64
#define HDIM  1024
#define GDIM  4096
#define VOCAB 32000
#define TBROW (T_LEN * BATCH)   // 4480

// ---------------------------------------------------------------------------
// fp32 -> bf16 hi/lo split (hi = rn(w), lo = rn(w - hi)); vectorized x4
// ---------------------------------------------------------------------------
__global__ void split_kernel(const float* __restrict__ w, bf16* __restrict__ hi,
                             bf16* __restrict__ lo, int n4) {
    int stride = gridDim.x * blockDim.x;
    for (int i = blockIdx.x * blockDim.x + threadIdx.x; i < n4; i += stride) {
        float4 v = reinterpret_cast<const float4*>(w)[i];
        bf16 h0 = (bf16)v.x, h1 = (bf16)v.y, h2 = (bf16)v.z, h3 = (bf16)v.w;
        bf16x4 hv = {h0, h1, h2, h3};
        bf16x4 lv = {(bf16)(v.x - (float)h0), (bf16)(v.y - (float)h1),
                     (bf16)(v.z - (float)h2), (bf16)(v.w - (float)h3)};
        reinterpret_cast<bf16x4*>(hi)[i] = hv;
        reinterpret_cast<bf16x4*>(lo)[i] = lv;
    }
}

__global__ void conv_kernel(const float* __restrict__ w, bf16* __restrict__ hi, int n4) {
    int stride = gridDim.x * blockDim.x;
    for (int i = blockIdx.x * blockDim.x + threadIdx.x; i < n4; i += stride) {
        float4 v = reinterpret_cast<const float4*>(w)[i];
        bf16x4 hv = {(bf16)v.x, (bf16)v.y, (bf16)v.z, (bf16)v.w};
        reinterpret_cast<bf16x4*>(hi)[i] = hv;
    }
}

// ---------------------------------------------------------------------------
// embedding gather -> xe hi/lo  (one block per (t,b) row)
// ---------------------------------------------------------------------------
__global__ void embed_kernel(const int* __restrict__ x, const float* __restrict__ emb,
                             bf16* __restrict__ xh, bf16* __restrict__ xl) {
    int row = blockIdx.x;
    int tok = x[row];
    const float4* src = reinterpret_cast<const float4*>(emb + (size_t)tok * HDIM);
    bf16x4* dh = reinterpret_cast<bf16x4*>(xh + (size_t)row * HDIM);
    bf16x4* dl = reinterpret_cast<bf16x4*>(xl + (size_t)row * HDIM);
    for (int i = threadIdx.x; i < HDIM / 4; i += blockDim.x) {
        float4 v = src[i];
        bf16 h0 = (bf16)v.x, h1 = (bf16)v.y, h2 = (bf16)v.z, h3 = (bf16)v.w;
        dh[i] = (bf16x4){h0, h1, h2, h3};
        dl[i] = (bf16x4){(bf16)(v.x - (float)h0), (bf16)(v.y - (float)h1),
                         (bf16)(v.z - (float)h2), (bf16)(v.w - (float)h3)};
    }
}

// ---------------------------------------------------------------------------
// state init: h0 -> h-state hi/lo (parity 0), c0 -> c-state (fp32)
// grid 768 x 256 == 3*64*1024 exactly
// ---------------------------------------------------------------------------
__global__ void init_kernel(const float* __restrict__ h0, const float* __restrict__ c0,
                            bf16* __restrict__ hsb, float* __restrict__ cst) {
    int i = blockIdx.x * blockDim.x + threadIdx.x;
    int l = i >> 16, r = i & 65535;
    float v = h0[i];
    bf16 h = (bf16)v;
    hsb[(size_t)((l * 2 + 0) * 2 + 0) * 65536 + r] = h;
    hsb[(size_t)((l * 2 + 0) * 2 + 1) * 65536 + r] = (bf16)(v - (float)h);
    cst[i] = c0[i];
}

// ---------------------------------------------------------------------------
// C[M x N](f32) = sum_passes A_p[M x K](bf16) * B_p[N x K](bf16)^T + bias[N]
// 128x128 tile, BK=64, 4 waves, 16x16x32 MFMA. grid = (N/128, M/128)
// ---------------------------------------------------------------------------
__global__ __launch_bounds__(256) void gemm_bt(
    const bf16* __restrict__ a0, const bf16* __restrict__ a1, const bf16* __restrict__ a2,
    const bf16* __restrict__ b0, const bf16* __restrict__ b1, const bf16* __restrict__ b2,
    int npass, int K, const float* __restrict__ bias, float* __restrict__ C, int ldc) {
    __shared__ __align__(16) bf16 As[128 * 64];
    __shared__ __align__(16) bf16 Bs[128 * 64];
    const int tid = threadIdx.x;
    const int wid = tid >> 6, lane = tid & 63;
    const int l15 = lane & 15, l4 = lane >> 4;
    const int m0 = blockIdx.y * 128, n0 = blockIdx.x * 128;
    const int wr = (wid >> 1) * 64, wc = (wid & 1) * 64;
    const int sr = tid >> 3, sc = (tid & 7) * 8;

    f32x4 acc[4][4];
#pragma unroll
    for (int i = 0; i < 4; ++i)
#pragma unroll
        for (int j = 0; j < 4; ++j) acc[i][j] = (f32x4){0.f, 0.f, 0.f, 0.f};

    for (int p = 0; p < npass; ++p) {
        const bf16* A = (p == 0) ? a0 : ((p == 1) ? a1 : a2);
        const bf16* B = (p == 0) ? b0 : ((p == 1) ? b1 : b2);
        for (int k0 = 0; k0 < K; k0 += 64) {
            __syncthreads();
#pragma unroll
            for (int rr = 0; rr < 128; rr += 32) {
                *reinterpret_cast<uint4*>(&As[(rr + sr) * 64 + sc]) =
                    *reinterpret_cast<const uint4*>(&A[(size_t)(m0 + rr + sr) * K + k0 + sc]);
                *reinterpret_cast<uint4*>(&Bs[(rr + sr) * 64 + sc]) =
                    *reinterpret_cast<const uint4*>(&B[(size_t)(n0 + rr + sr) * K + k0 + sc]);
            }
            __syncthreads();
#pragma unroll
            for (int ks = 0; ks < 2; ++ks) {
                const int kb = ks * 32 + l4 * 8;
                bf16x8 af[4], bfr[4];
#pragma unroll
                for (int mi = 0; mi < 4; ++mi)
                    af[mi] = *reinterpret_cast<const bf16x8*>(&As[(wr + mi * 16 + l15) * 64 + kb]);
#pragma unroll
                for (int ni = 0; ni < 4; ++ni)
                    bfr[ni] = *reinterpret_cast<const bf16x8*>(&Bs[(wc + ni * 16 + l15) * 64 + kb]);
#pragma unroll
                for (int mi = 0; mi < 4; ++mi)
#pragma unroll
                    for (int ni = 0; ni < 4; ++ni)
                        acc[mi][ni] = __builtin_amdgcn_mfma_f32_16x16x32_bf16(
                            af[mi], bfr[ni], acc[mi][ni], 0, 0, 0);
            }
        }
    }
#pragma unroll
    for (int ni = 0; ni < 4; ++ni) {
        const int col = n0 + wc + ni * 16 + l15;
        const float bv = bias[col];
#pragma unroll
        for (int mi = 0; mi < 4; ++mi) {
            const int row0 = m0 + wr + mi * 16 + l4 * 4;
#pragma unroll
            for (int r = 0; r < 4; ++r)
                C[(size_t)(row0 + r) * ldc + col] = acc[mi][ni][r] + bv;
        }
    }
}

// ---------------------------------------------------------------------------
// Fused LSTM cell: p = [x*Wi^T] + h*Wh^T + biases (+px), gates, state update.
// grid 64 blocks (16 gate-cols each), 512 threads = 8 waves:
//   wave = (khalf, quarter); split-bf16 -> 3 MFMA passes per operand pair.
// ---------------------------------------------------------------------------
__global__ __launch_bounds__(512) void cell_kernel(
    const bf16* __restrict__ xh, const bf16* __restrict__ xl,
    const bf16* __restrict__ hh, const bf16* __restrict__ hl,
    const bf16* __restrict__ Wih, const bf16* __restrict__ Wil,
    const bf16* __restrict__ Whh, const bf16* __restrict__ Whl,
    const float* __restrict__ px, const float* __restrict__ bi, const float* __restrict__ bh,
    float* __restrict__ c, bf16* __restrict__ h2h, bf16* __restrict__ h2l,
    bf16* __restrict__ outh) {
    __shared__ __align__(16) bf16 Ah[64 * 128];
    __shared__ __align__(16) bf16 Al[64 * 128];
    const int tid = threadIdx.x;
    const int wid = tid >> 6, lane = tid & 63;
    const int l15 = lane & 15, l4 = lane >> 4;
    const int q = wid & 3, half = wid >> 2;
    const int j0 = blockIdx.x * 16;
    const int wcol = q * 1024 + j0;
    const int sr = tid >> 3, ss = tid & 7;

    f32x4 acc[4];
#pragma unroll
    for (int mi = 0; mi < 4; ++mi) acc[mi] = (f32x4){0.f, 0.f, 0.f, 0.f};

    for (int g = 0; g < 2; ++g) {
        const bf16* At_h = g ? hh : xh;
        if (At_h == nullptr) continue;
        const bf16* At_l = g ? hl : xl;
        const bf16* Bt_h = g ? Whh : Wih;
        const bf16* Bt_l = g ? Whl : Wil;
        for (int c0 = 0; c0 < HDIM; c0 += 128) {
            __syncthreads();
#pragma unroll
            for (int round = 0; round < 2; ++round) {
                const int kc = ss * 8 + round * 64;
                *reinterpret_cast<uint4*>(&Ah[sr * 128 + kc]) =
                    *reinterpret_cast<const uint4*>(&At_h[(size_t)sr * HDIM + c0 + kc]);
                *reinterpret_cast<uint4*>(&Al[sr * 128 + kc]) =
                    *reinterpret_cast<const uint4*>(&At_l[(size_t)sr * HDIM + c0 + kc]);
            }
            __syncthreads();
            // B fragments for this wave's K-half, direct from global (L2/L3)
            bf16x8 bhf[2], blf[2];
#pragma unroll
            for (int u = 0; u < 2; ++u) {
                const int kb = (half * 2 + u) * 32 + l4 * 8;
                bhf[u] = *reinterpret_cast<const bf16x8*>(
                    &Bt_h[(size_t)(wcol + l15) * HDIM + c0 + kb]);
                blf[u] = *reinterpret_cast<const bf16x8*>(
                    &Bt_l[(size_t)(wcol + l15) * HDIM + c0 + kb]);
            }
#pragma unroll
            for (int u = 0; u < 2; ++u) {
                const int kb = (half * 2 + u) * 32 + l4 * 8;
#pragma unroll
                for (int mi = 0; mi < 4; ++mi) {
                    bf16x8 ah8 = *reinterpret_cast<const bf16x8*>(&Ah[(mi * 16 + l15) * 128 + kb]);
                    bf16x8 al8 = *reinterpret_cast<const bf16x8*>(&Al[(mi * 16 + l15) * 128 + kb]);
                    acc[mi] = __builtin_amdgcn_mfma_f32_16x16x32_bf16(ah8, bhf[u], acc[mi], 0, 0, 0);
                    acc[mi] = __builtin_amdgcn_mfma_f32_16x16x32_bf16(ah8, blf[u], acc[mi], 0, 0, 0);
                    acc[mi] = __builtin_amdgcn_mfma_f32_16x16x32_bf16(al8, bhf[u], acc[mi], 0, 0, 0);
                }
            }
        }
    }

    // ---- epilogue: cross-wave p exchange in LDS, then gates ----
    __syncthreads();
    float* pex = reinterpret_cast<float*>(Ah);  // [4 quarters][64 rows][16 cols] = 16 KB
    if (half == 0) {
        const int col = wcol + l15;
        const float bias = bh[col] + (bi ? bi[col] : 0.f);
#pragma unroll
        for (int mi = 0; mi < 4; ++mi)
#pragma unroll
            for (int r = 0; r < 4; ++r) {
                const int row = mi * 16 + l4 * 4 + r;
                float v = acc[mi][r] + bias;
                if (px) v += px[(size_t)row * GDIM + col];
                pex[(q * 64 + row) * 16 + l15] = v;
            }
    }
    __syncthreads();
    if (half == 1) {
#pragma unroll
        for (int mi = 0; mi < 4; ++mi)
#pragma unroll
            for (int r = 0; r < 4; ++r) {
                const int row = mi * 16 + l4 * 4 + r;
                pex[(q * 64 + row) * 16 + l15] += acc[mi][r];
            }
    }
    __syncthreads();
    for (int e = tid; e < 1024; e += 512) {
        const int b = e >> 4, jl = e & 15;
        const float pi = pex[(0 * 64 + b) * 16 + jl];
        const float pf = pex[(1 * 64 + b) * 16 + jl];
        const float po = pex[(2 * 64 + b) * 16 + jl];
        const float pg = pex[(3 * 64 + b) * 16 + jl];
        const float ig = 1.f / (1.f + expf(-pi));
        const float fg = 1.f / (1.f + expf(-pf));
        const float og = 1.f / (1.f + expf(-po));
        const float gg = tanhf(pg);
        const int idx = b * HDIM + j0 + jl;
        const float c2 = fg * c[idx] + ig * gg;
        const float h2v = og * tanhf(c2);
        c[idx] = c2;
        const bf16 hhi = (bf16)h2v;
        h2h[idx] = hhi;
        h2l[idx] = (bf16)(h2v - (float)hhi);
        if (outh) outh[idx] = hhi;
    }
}

// ---------------------------------------------------------------------------
extern "C" void kernel_launch(void* const* d_in, const int* in_sizes, int n_in,
                              void* d_out, int out_size, void* d_ws, size_t ws_size,
                              hipStream_t stream) {
    (void)in_sizes; (void)n_in; (void)out_size; (void)ws_size;
    const int*   x   = (const int*)d_in[0];
    const float* h0  = (const float*)d_in[1];
    const float* c0  = (const float*)d_in[2];
    const float* emb = (const float*)d_in[3];
    const float* W[6] = { (const float*)d_in[4],  (const float*)d_in[6],
                          (const float*)d_in[8],  (const float*)d_in[10],
                          (const float*)d_in[12], (const float*)d_in[14] };
    const float* bi0 = (const float*)d_in[5];
    const float* bh0 = (const float*)d_in[7];
    const float* bi1 = (const float*)d_in[9];
    const float* bh1 = (const float*)d_in[11];
    const float* bi2 = (const float*)d_in[13];
    const float* bh2 = (const float*)d_in[15];
    const float* Wd  = (const float*)d_in[16];
    const float* bd  = (const float*)d_in[17];

    char* ws = (char*)d_ws;
    size_t off = 0;
    float* px0 = (float*)(ws + off); off += (size_t)TBROW * GDIM * 4;          // 73.4 MB
    bf16* wsp[12];
    for (int i = 0; i < 12; ++i) { wsp[i] = (bf16*)(ws + off); off += (size_t)GDIM * HDIM * 2; }
    bf16* wdb  = (bf16*)(ws + off); off += (size_t)VOCAB * HDIM * 2;           // 65.5 MB
    bf16* xeh  = (bf16*)(ws + off); off += (size_t)TBROW * HDIM * 2;
    bf16* xel  = (bf16*)(ws + off); off += (size_t)TBROW * HDIM * 2;
    bf16* outh = (bf16*)(ws + off); off += (size_t)TBROW * HDIM * 2;
    bf16* hsb  = (bf16*)(ws + off); off += (size_t)12 * BATCH * HDIM * 2;
    float* cst = (float*)(ws + off); off += (size_t)3 * BATCH * HDIM * 4;

    auto hs = [&](int l, int p, int hl) {
        return hsb + (((size_t)l * 2 + p) * 2 + hl) * BATCH * HDIM;
    };

    // weight hi/lo splits: wsp[0..1]=Wi0, [2..3]=Wh0, [4..5]=Wi1, [6..7]=Wh1,
    //                      [8..9]=Wi2, [10..11]=Wh2
    for (int i = 0; i < 6; ++i)
        split_kernel<<<1024, 256, 0, stream>>>(W[i], wsp[2 * i], wsp[2 * i + 1],
                                               GDIM * HDIM / 4);
    conv_kernel<<<2048, 256, 0, stream>>>(Wd, wdb, VOCAB * HDIM / 4);
    embed_kernel<<<TBROW, 256, 0, stream>>>(x, emb, xeh, xel);
    init_kernel<<<768, 256, 0, stream>>>(h0, c0, hsb, cst);

    // px0 = xe @ Wi0^T + bi0  (split-3: (xeh,Wi0h),(xel,Wi0h),(xeh,Wi0l))
    dim3 gpx(GDIM / 128, TBROW / 128);
    gemm_bt<<<gpx, 256, 0, stream>>>(xeh, xel, xeh, wsp[0], wsp[0], wsp[1],
                                     3, HDIM, bi0, px0, GDIM);

    for (int t = 0; t < T_LEN; ++t) {
        const int p = t & 1;
        cell_kernel<<<64, 512, 0, stream>>>(
            nullptr, nullptr, hs(0, p, 0), hs(0, p, 1),
            nullptr, nullptr, wsp[2], wsp[3],
            px0 + (size_t)t * BATCH * GDIM, nullptr, bh0,
            cst, hs(0, 1 - p, 0), hs(0, 1 - p, 1), nullptr);
        cell_kernel<<<64, 512, 0, stream>>>(
            hs(0, 1 - p, 0), hs(0, 1 - p, 1), hs(1, p, 0), hs(1, p, 1),
            wsp[4], wsp[5], wsp[6], wsp[7],
            nullptr, bi1, bh1,
            cst + BATCH * HDIM, hs(1, 1 - p, 0), hs(1, 1 - p, 1), nullptr);
        cell_kernel<<<64, 512, 0, stream>>>(
            hs(1, 1 - p, 0), hs(1, 1 - p, 1), hs(2, p, 0), hs(2, p, 1),
            wsp[8], wsp[9], wsp[10], wsp[11],
            nullptr, bi2, bh2,
            cst + 2 * BATCH * HDIM, hs(2, 1 - p, 0), hs(2, 1 - p, 1),
            outh + (size_t)t * BATCH * HDIM);
    }

    // decoder: d_out = outh @ Wd^T + bd   (plain bf16, single pass)
    dim3 gdec(VOCAB / 128, TBROW / 128);
    gemm_bt<<<gdec, 256, 0, stream>>>(outh, nullptr, nullptr, wdb, nullptr, nullptr,
                                      1, HDIM, bd, (float*)d_out, VOCAB);
}

// Round 2
// 7101.976 us; speedup vs baseline: 1.4309x; 1.4309x over previous
//
#include <hip/hip_runtime.h>

typedef __bf16 bf16;
typedef __bf16 bf16x8 __attribute__((ext_vector_type(8)));
typedef __bf16 bf16x4 __attribute__((ext_vector_type(4)));
typedef float  f32x4  __attribute__((ext_vector_type(4)));

#define T_LEN 70
#define BATCH 64
#define HDIM  1024
#define GDIM  4096
#define VOCAB 32000
#define TBROW (T_LEN * BATCH)   // 4480

// ---------------------------------------------------------------------------
// fp32 -> bf16 hi/lo split
// ---------------------------------------------------------------------------
__global__ void split_kernel(const float* __restrict__ w, bf16* __restrict__ hi,
                             bf16* __restrict__ lo, int n4) {
    int stride = gridDim.x * blockDim.x;
    for (int i = blockIdx.x * blockDim.x + threadIdx.x; i < n4; i += stride) {
        float4 v = reinterpret_cast<const float4*>(w)[i];
        bf16 h0 = (bf16)v.x, h1 = (bf16)v.y, h2 = (bf16)v.z, h3 = (bf16)v.w;
        bf16x4 hv = {h0, h1, h2, h3};
        bf16x4 lv = {(bf16)(v.x - (float)h0), (bf16)(v.y - (float)h1),
                     (bf16)(v.z - (float)h2), (bf16)(v.w - (float)h3)};
        reinterpret_cast<bf16x4*>(hi)[i] = hv;
        reinterpret_cast<bf16x4*>(lo)[i] = lv;
    }
}

__global__ void conv_kernel(const float* __restrict__ w, bf16* __restrict__ hi, int n4) {
    int stride = gridDim.x * blockDim.x;
    for (int i = blockIdx.x * blockDim.x + threadIdx.x; i < n4; i += stride) {
        float4 v = reinterpret_cast<const float4*>(w)[i];
        bf16x4 hv = {(bf16)v.x, (bf16)v.y, (bf16)v.z, (bf16)v.w};
        reinterpret_cast<bf16x4*>(hi)[i] = hv;
    }
}

__global__ void embed_kernel(const int* __restrict__ x, const float* __restrict__ emb,
                             bf16* __restrict__ xh, bf16* __restrict__ xl) {
    int row = blockIdx.x;
    int tok = x[row];
    const float4* src = reinterpret_cast<const float4*>(emb + (size_t)tok * HDIM);
    bf16x4* dh = reinterpret_cast<bf16x4*>(xh + (size_t)row * HDIM);
    bf16x4* dl = reinterpret_cast<bf16x4*>(xl + (size_t)row * HDIM);
    for (int i = threadIdx.x; i < HDIM / 4; i += blockDim.x) {
        float4 v = src[i];
        bf16 h0 = (bf16)v.x, h1 = (bf16)v.y, h2 = (bf16)v.z, h3 = (bf16)v.w;
        dh[i] = (bf16x4){h0, h1, h2, h3};
        dl[i] = (bf16x4){(bf16)(v.x - (float)h0), (bf16)(v.y - (float)h1),
                         (bf16)(v.z - (float)h2), (bf16)(v.w - (float)h3)};
    }
}

__global__ void init_kernel(const float* __restrict__ h0, const float* __restrict__ c0,
                            bf16* __restrict__ hsb, float* __restrict__ cst) {
    int i = blockIdx.x * blockDim.x + threadIdx.x;
    int l = i >> 16, r = i & 65535;
    float v = h0[i];
    bf16 h = (bf16)v;
    hsb[(size_t)((l * 2 + 0) * 2 + 0) * 65536 + r] = h;
    hsb[(size_t)((l * 2 + 0) * 2 + 1) * 65536 + r] = (bf16)(v - (float)h);
    cst[i] = c0[i];
}

// ---------------------------------------------------------------------------
// GEMM C = sum_p A_p B_p^T + bias, 128x128 tile, with XCD-aware remap:
// per-XCD contiguous M-range, N fastest -> A panels L2-hot, B streams L3 once.
// ---------------------------------------------------------------------------
__global__ __launch_bounds__(256) void gemm_bt(
    const bf16* __restrict__ a0, const bf16* __restrict__ a1, const bf16* __restrict__ a2,
    const bf16* __restrict__ b0, const bf16* __restrict__ b1, const bf16* __restrict__ b2,
    int npass, int K, const float* __restrict__ bias, float* __restrict__ C, int ldc) {
    __shared__ __align__(16) bf16 As[128 * 64];
    __shared__ __align__(16) bf16 Bs[128 * 64];
    const int tid = threadIdx.x;
    const int wid = tid >> 6, lane = tid & 63;
    const int l15 = lane & 15, l4 = lane >> 4;

    // bijective XCD swizzle (m204), then m-major-per-XCD / n-fastest order
    const int nbx = gridDim.x, nwg = nbx * gridDim.y;
    const int flat = blockIdx.y * nbx + blockIdx.x;
    const int xcd = flat & 7, o8 = flat >> 3;
    const int q8 = nwg >> 3, r8 = nwg & 7;
    const int wg = (xcd < r8 ? xcd * (q8 + 1) : r8 * (q8 + 1) + (xcd - r8) * q8) + o8;
    const int m0 = (wg / nbx) * 128, n0 = (wg % nbx) * 128;

    const int wr = (wid >> 1) * 64, wc = (wid & 1) * 64;
    const int sr = tid >> 3, sc = (tid & 7) * 8;

    f32x4 acc[4][4];
#pragma unroll
    for (int i = 0; i < 4; ++i)
#pragma unroll
        for (int j = 0; j < 4; ++j) acc[i][j] = (f32x4){0.f, 0.f, 0.f, 0.f};

    for (int p = 0; p < npass; ++p) {
        const bf16* A = (p == 0) ? a0 : ((p == 1) ? a1 : a2);
        const bf16* B = (p == 0) ? b0 : ((p == 1) ? b1 : b2);
        for (int k0 = 0; k0 < K; k0 += 64) {
            __syncthreads();
#pragma unroll
            for (int rr = 0; rr < 128; rr += 32) {
                *reinterpret_cast<uint4*>(&As[(rr + sr) * 64 + sc]) =
                    *reinterpret_cast<const uint4*>(&A[(size_t)(m0 + rr + sr) * K + k0 + sc]);
                *reinterpret_cast<uint4*>(&Bs[(rr + sr) * 64 + sc]) =
                    *reinterpret_cast<const uint4*>(&B[(size_t)(n0 + rr + sr) * K + k0 + sc]);
            }
            __syncthreads();
#pragma unroll
            for (int ks = 0; ks < 2; ++ks) {
                const int kb = ks * 32 + l4 * 8;
                bf16x8 af[4], bfr[4];
#pragma unroll
                for (int mi = 0; mi < 4; ++mi)
                    af[mi] = *reinterpret_cast<const bf16x8*>(&As[(wr + mi * 16 + l15) * 64 + kb]);
#pragma unroll
                for (int ni = 0; ni < 4; ++ni)
                    bfr[ni] = *reinterpret_cast<const bf16x8*>(&Bs[(wc + ni * 16 + l15) * 64 + kb]);
#pragma unroll
                for (int mi = 0; mi < 4; ++mi)
#pragma unroll
                    for (int ni = 0; ni < 4; ++ni)
                        acc[mi][ni] = __builtin_amdgcn_mfma_f32_16x16x32_bf16(
                            af[mi], bfr[ni], acc[mi][ni], 0, 0, 0);
            }
        }
    }
#pragma unroll
    for (int ni = 0; ni < 4; ++ni) {
        const int col = n0 + wc + ni * 16 + l15;
        const float bv = bias[col];
#pragma unroll
        for (int mi = 0; mi < 4; ++mi) {
            const int row0 = m0 + wr + mi * 16 + l4 * 4;
#pragma unroll
            for (int r = 0; r < 4; ++r)
                C[(size_t)(row0 + r) * ldc + col] = acc[mi][ni][r] + bv;
        }
    }
}

// ---------------------------------------------------------------------------
// Fused LSTM cell v2.
// 128 blocks x 512 thr (8 waves). Block owns 8 gate-cols in each of the 4
// quarters (32 gate outputs x 64 batch rows). Wave (wm 0..3, wn 0..1) computes
// one 16x16 MFMA tile: rows wm*16.., cols = quarters {2wn,2wn+1} x 8.
// K loop: chunks of 128, double-buffered XOR-swizzled LDS for A (hi+lo),
// B fragments double-buffered in registers. One barrier per chunk.
// ---------------------------------------------------------------------------
struct AReg { uint4 h0, h1, l0, l1; };

__global__ __launch_bounds__(512) void cell2(
    const bf16* __restrict__ xh, const bf16* __restrict__ xl,
    const bf16* __restrict__ hh, const bf16* __restrict__ hl,
    const bf16* __restrict__ Wih, const bf16* __restrict__ Wil,
    const bf16* __restrict__ Whh, const bf16* __restrict__ Whl,
    const float* __restrict__ px, const float* __restrict__ bi, const float* __restrict__ bh,
    float* __restrict__ c, bf16* __restrict__ h2h, bf16* __restrict__ h2l,
    bf16* __restrict__ outh) {
    __shared__ __align__(16) char smem[65536];
    // layout: Ah buf0 [0,16K) | Ah buf1 [16K,32K) | Al buf0 [32K,48K) | Al buf1 [48K,64K)

    const int tid = threadIdx.x;
    const int wid = tid >> 6, lane = tid & 63;
    const int l15 = lane & 15, l4 = lane >> 4;
    const int wm = wid & 3, wn = wid >> 2;
    const int j0 = blockIdx.x * 8;
    const int lq = wn * 2 + (l15 >> 3);            // quarter 0..3
    const int lcol = lq * 1024 + j0 + (l15 & 7);   // gate column / weight row
    const int sr = tid >> 3, ss = tid & 7;

    // operand schedule: chunks [0, n): op0 = (x if present else h), op1 = h
    const bf16* A0h = xh ? xh : hh;
    const bf16* A0l = xh ? xl : hl;
    const bf16* B0h = xh ? Wih : Whh;
    const bf16* B0l = xh ? Wil : Whl;
    const int nchunks = xh ? 16 : 8;

    // staging write addresses (swizzled)
    const int swz_s = (sr & 7) << 4;
    const int wc0 = (ss * 16) ^ swz_s;
    const int wc1 = (ss * 16 + 128) ^ swz_s;
    const int wrow = sr * 256;
    // fragment read addresses
    const int frow = (wm * 16 + l15) * 256;
    const int swz_r = (l15 & 7) << 4;

    f32x4 acc = (f32x4){0.f, 0.f, 0.f, 0.f};

#define SRC_AH(cc) (((cc) >= 8) ? hh : A0h)
#define SRC_AL(cc) (((cc) >= 8) ? hl : A0l)
#define SRC_BH(cc) (((cc) >= 8) ? Whh : B0h)
#define SRC_BL(cc) (((cc) >= 8) ? Whl : B0l)
#define C0(cc) (((cc) & 7) * 128)

#define LOADA(cc, RA)                                                              \
    {                                                                              \
        const size_t e0 = (size_t)sr * HDIM + C0(cc) + ss * 8;                     \
        const bf16* ph = SRC_AH(cc);                                               \
        const bf16* pl = SRC_AL(cc);                                               \
        RA.h0 = *reinterpret_cast<const uint4*>(ph + e0);                          \
        RA.h1 = *reinterpret_cast<const uint4*>(ph + e0 + 64);                     \
        RA.l0 = *reinterpret_cast<const uint4*>(pl + e0);                          \
        RA.l1 = *reinterpret_cast<const uint4*>(pl + e0 + 64);                     \
    }

#define LOADB(cc, BH, BL)                                                          \
    {                                                                              \
        const bf16* pbh = SRC_BH(cc);                                              \
        const bf16* pbl = SRC_BL(cc);                                              \
        const size_t eb = (size_t)lcol * HDIM + C0(cc) + l4 * 8;                   \
        _Pragma("unroll") for (int ks = 0; ks < 4; ++ks) {                         \
            BH[ks] = *reinterpret_cast<const bf16x8*>(pbh + eb + ks * 32);         \
            BL[ks] = *reinterpret_cast<const bf16x8*>(pbl + eb + ks * 32);         \
        }                                                                          \
    }

#define STOREA(buf, RA)                                                            \
    {                                                                              \
        char* bh_ = smem + (buf) * 16384 + wrow;                                   \
        char* bl_ = smem + 32768 + (buf) * 16384 + wrow;                           \
        *reinterpret_cast<uint4*>(bh_ + wc0) = RA.h0;                              \
        *reinterpret_cast<uint4*>(bh_ + wc1) = RA.h1;                              \
        *reinterpret_cast<uint4*>(bl_ + wc0) = RA.l0;                              \
        *reinterpret_cast<uint4*>(bl_ + wc1) = RA.l1;                              \
    }

#define COMPUTE(buf, BH, BL)                                                       \
    {                                                                              \
        const char* bh_ = smem + (buf) * 16384 + frow;                             \
        const char* bl_ = smem + 32768 + (buf) * 16384 + frow;                     \
        _Pragma("unroll") for (int ks = 0; ks < 4; ++ks) {                         \
            const int cb = (ks * 64 + l4 * 16) ^ swz_r;                            \
            bf16x8 ah8 = *reinterpret_cast<const bf16x8*>(bh_ + cb);               \
            bf16x8 al8 = *reinterpret_cast<const bf16x8*>(bl_ + cb);               \
            acc = __builtin_amdgcn_mfma_f32_16x16x32_bf16(ah8, BH[ks], acc, 0, 0, 0); \
            acc = __builtin_amdgcn_mfma_f32_16x16x32_bf16(ah8, BL[ks], acc, 0, 0, 0); \
            acc = __builtin_amdgcn_mfma_f32_16x16x32_bf16(al8, BH[ks], acc, 0, 0, 0); \
        }                                                                          \
    }

    AReg rA0, rA1;
    bf16x8 rB0h[4], rB0l[4], rB1h[4], rB1l[4];

    // prologue: chunk 0 into buf0/regs
    LOADA(0, rA0);
    LOADB(0, rB0h, rB0l);
    STOREA(0, rA0);
    __syncthreads();

    for (int cc = 0; cc < nchunks; cc += 2) {
        // even chunk cc: compute buf0/B0, prefetch cc+1 -> rA1/rB1, stage buf1
        LOADA(cc + 1, rA1);
        LOADB(cc + 1, rB1h, rB1l);
        COMPUTE(0, rB0h, rB0l);
        STOREA(1, rA1);
        __syncthreads();
        // odd chunk cc+1: compute buf1/B1, prefetch cc+2 -> rA0/rB0, stage buf0
        if (cc + 2 < nchunks) {
            LOADA(cc + 2, rA0);
            LOADB(cc + 2, rB0h, rB0l);
            COMPUTE(1, rB1h, rB1l);
            STOREA(0, rA0);
        } else {
            COMPUTE(1, rB1h, rB1l);
        }
        __syncthreads();
    }

    // ---- epilogue: single LDS exchange, then gates ----
    float* pex = reinterpret_cast<float*>(smem);   // [64 rows][32 cols]
    {
        const float bias = bh[lcol] + (bi ? bi[lcol] : 0.f);
        const int col = wn * 16 + l15;
#pragma unroll
        for (int r = 0; r < 4; ++r) {
            const int row = wm * 16 + l4 * 4 + r;
            float v = acc[r] + bias;
            if (px) v += px[(size_t)row * GDIM + lcol];
            pex[row * 32 + col] = v;
        }
    }
    __syncthreads();
    {
        const int b = tid >> 3, jl = tid & 7;
        const float pi = pex[b * 32 + jl];
        const float pf = pex[b * 32 + 8 + jl];
        const float po = pex[b * 32 + 16 + jl];
        const float pg = pex[b * 32 + 24 + jl];
        const float ig = 1.f / (1.f + expf(-pi));
        const float fg = 1.f / (1.f + expf(-pf));
        const float og = 1.f / (1.f + expf(-po));
        const float gg = tanhf(pg);
        const int idx = b * HDIM + j0 + jl;
        const float c2 = fg * c[idx] + ig * gg;
        const float h2v = og * tanhf(c2);
        c[idx] = c2;
        const bf16 hhi = (bf16)h2v;
        h2h[idx] = hhi;
        h2l[idx] = (bf16)(h2v - (float)hhi);
        if (outh) outh[idx] = hhi;
    }
#undef SRC_AH
#undef SRC_AL
#undef SRC_BH
#undef SRC_BL
#undef C0
#undef LOADA
#undef LOADB
#undef STOREA
#undef COMPUTE
}

// ---------------------------------------------------------------------------
extern "C" void kernel_launch(void* const* d_in, const int* in_sizes, int n_in,
                              void* d_out, int out_size, void* d_ws, size_t ws_size,
                              hipStream_t stream) {
    (void)in_sizes; (void)n_in; (void)out_size; (void)ws_size;
    const int*   x   = (const int*)d_in[0];
    const float* h0  = (const float*)d_in[1];
    const float* c0  = (const float*)d_in[2];
    const float* emb = (const float*)d_in[3];
    const float* W[6] = { (const float*)d_in[4],  (const float*)d_in[6],
                          (const float*)d_in[8],  (const float*)d_in[10],
                          (const float*)d_in[12], (const float*)d_in[14] };
    const float* bi0 = (const float*)d_in[5];
    const float* bh0 = (const float*)d_in[7];
    const float* bi1 = (const float*)d_in[9];
    const float* bh1 = (const float*)d_in[11];
    const float* bi2 = (const float*)d_in[13];
    const float* bh2 = (const float*)d_in[15];
    const float* Wd  = (const float*)d_in[16];
    const float* bd  = (const float*)d_in[17];

    char* ws = (char*)d_ws;
    size_t off = 0;
    float* px0 = (float*)(ws + off); off += (size_t)TBROW * GDIM * 4;
    bf16* wsp[12];
    for (int i = 0; i < 12; ++i) { wsp[i] = (bf16*)(ws + off); off += (size_t)GDIM * HDIM * 2; }
    bf16* wdb  = (bf16*)(ws + off); off += (size_t)VOCAB * HDIM * 2;
    bf16* xeh  = (bf16*)(ws + off); off += (size_t)TBROW * HDIM * 2;
    bf16* xel  = (bf16*)(ws + off); off += (size_t)TBROW * HDIM * 2;
    bf16* outh = (bf16*)(ws + off); off += (size_t)TBROW * HDIM * 2;
    bf16* hsb  = (bf16*)(ws + off); off += (size_t)12 * BATCH * HDIM * 2;
    float* cst = (float*)(ws + off); off += (size_t)3 * BATCH * HDIM * 4;

    auto hs = [&](int l, int p, int hl) {
        return hsb + (((size_t)l * 2 + p) * 2 + hl) * BATCH * HDIM;
    };

    for (int i = 0; i < 6; ++i)
        split_kernel<<<1024, 256, 0, stream>>>(W[i], wsp[2 * i], wsp[2 * i + 1],
                                               GDIM * HDIM / 4);
    conv_kernel<<<2048, 256, 0, stream>>>(Wd, wdb, VOCAB * HDIM / 4);
    embed_kernel<<<TBROW, 256, 0, stream>>>(x, emb, xeh, xel);
    init_kernel<<<768, 256, 0, stream>>>(h0, c0, hsb, cst);

    dim3 gpx(GDIM / 128, TBROW / 128);
    gemm_bt<<<gpx, 256, 0, stream>>>(xeh, xel, xeh, wsp[0], wsp[0], wsp[1],
                                     3, HDIM, bi0, px0, GDIM);

    for (int t = 0; t < T_LEN; ++t) {
        const int p = t & 1;
        cell2<<<128, 512, 0, stream>>>(
            nullptr, nullptr, hs(0, p, 0), hs(0, p, 1),
            nullptr, nullptr, wsp[2], wsp[3],
            px0 + (size_t)t * BATCH * GDIM, nullptr, bh0,
            cst, hs(0, 1 - p, 0), hs(0, 1 - p, 1), nullptr);
        cell2<<<128, 512, 0, stream>>>(
            hs(0, 1 - p, 0), hs(0, 1 - p, 1), hs(1, p, 0), hs(1, p, 1),
            wsp[4], wsp[5], wsp[6], wsp[7],
            nullptr, bi1, bh1,
            cst + BATCH * HDIM, hs(1, 1 - p, 0), hs(1, 1 - p, 1), nullptr);
        cell2<<<128, 512, 0, stream>>>(
            hs(1, 1 - p, 0), hs(1, 1 - p, 1), hs(2, p, 0), hs(2, p, 1),
            wsp[8], wsp[9], wsp[10], wsp[11],
            nullptr, bi2, bh2,
            cst + 2 * BATCH * HDIM, hs(2, 1 - p, 0), hs(2, 1 - p, 1),
            outh + (size_t)t * BATCH * HDIM);
    }

    dim3 gdec(VOCAB / 128, TBROW / 128);
    gemm_bt<<<gdec, 256, 0, stream>>>(outh, nullptr, nullptr, wdb, nullptr, nullptr,
                                      1, HDIM, bd, (float*)d_out, VOCAB);
}